// Round 1
// 254.890 us; speedup vs baseline: 1.0618x; 1.0618x over previous
//
#include <hip/hip_runtime.h>
#include <hip/hip_fp16.h>
#include <cstdint>
#include <cstddef>

// DenseCaps dynamic routing, MI355X.
// B=256, R=2048, NC=10, OUT=16, IN=8, 3 routing iters.
//
// R3 structure: batch processed in TWO halves of 128 so the fp16 u_hat slab
// (84 MB/half) stays resident in the 256 MB Infinity Cache across its 4
// consumer passes. U layout is [r][b_local][160] (fp16); the producer
// accumulates outputs in registers, transposes through LDS (stride-44-dword
// rows -> line-rate b128 LDS ops), and flushes fully coalesced dwordx4
// stores (fixes the 8B-scatter store bottleneck: 200MB WRITE_SIZE @3.5TB/s).
// c0-softmax and squash are fused into the passes via an s0..s3 buffer chain
// (pass k computes v=squash(s_{k-1}) at block start, accumulates into s_k).
//
// bB (routing logits) aliases the c-region of d_out; P3 overwrites it with c.

#define B_   256
#define R_   2048
#define NC_  10
#define OD_  16
#define IN_  8
#define BH_  128          // batch half
#define UROW 80           // dwords per (r,b) u_hat row (160 fp16)

__device__ __forceinline__ float rsum16(float x){
  x += __shfl_xor(x, 1, 16);
  x += __shfl_xor(x, 2, 16);
  x += __shfl_xor(x, 4, 16);
  x += __shfl_xor(x, 8, 16);
  return x;
}
__device__ __forceinline__ float rmax16(float x){
  x = fmaxf(x, __shfl_xor(x, 1, 16));
  x = fmaxf(x, __shfl_xor(x, 2, 16));
  x = fmaxf(x, __shfl_xor(x, 4, 16));
  x = fmaxf(x, __shfl_xor(x, 8, 16));
  return x;
}
__device__ __forceinline__ unsigned pack_f16(float a, float b){
  __half2 h = __floats2half2_rn(a, b);
  return *(unsigned*)&h;
}
__device__ __forceinline__ void unpack8(uint4 d, float* f){
  float2 t;
  t = __half22float2(*(__half2*)&d.x); f[0] = t.x; f[1] = t.y;
  t = __half22float2(*(__half2*)&d.y); f[2] = t.x; f[3] = t.y;
  t = __half22float2(*(__half2*)&d.z); f[4] = t.x; f[5] = t.y;
  t = __half22float2(*(__half2*)&d.w); f[6] = t.x; f[7] = t.y;
}

// ---------- u_hat producer: one block per route r, one batch-half ----------
// thread = (nh in {0,1}, bl in [0,128)): computes the 80 outputs (5 classes)
// of (b0+bl, r) for column-half nh, i.e. global dwords [40*(2*bl+nh), +40)
// of row r. W[r] staged in LDS (all-lane broadcast reads, conflict-free).
// Results held in 40 VGPRs, staged to LDS rows of 44 dwords (16B-aligned,
// bank-rotating), flushed as 2560 coalesced dwordx4 stores per block.
__global__ __launch_bounds__(256) void uhat_kernel(const float* __restrict__ x,
                                                   const float* __restrict__ W,
                                                   uint32_t* __restrict__ U,
                                                   int b0){
  const int r = blockIdx.x;
  __shared__ float Wl[IN_ * 160];        // 5 KB
  __shared__ uint32_t St[256 * 44];      // 45 KB transpose staging
  {
    const float4* Wg = (const float4*)(W + (size_t)r * (IN_ * 160));
    float4* Wl4 = (float4*)Wl;
    for (int i = threadIdx.x; i < 320; i += 256) Wl4[i] = Wg[i];
  }
  __syncthreads();
  const int nh = threadIdx.x >> 7;       // waves 0-1: nh=0, waves 2-3: nh=1
  const int bl = threadIdx.x & 127;
  const float4* xp = (const float4*)(x + ((size_t)(b0 + bl) * R_ + r) * IN_);
  float4 xa = xp[0], xb = xp[1];
  float xr[8] = {xa.x, xa.y, xa.z, xa.w, xb.x, xb.y, xb.z, xb.w};
  const float4* Wl4 = (const float4*)Wl;
  uint32_t res[40];
  #pragma unroll
  for (int co = 0; co < 20; ++co){
    float4 u = make_float4(0.f, 0.f, 0.f, 0.f);
    #pragma unroll
    for (int i = 0; i < 8; ++i){
      float4 w = Wl4[i * 40 + nh * 20 + co];   // wave-uniform addr: broadcast
      u.x = fmaf(xr[i], w.x, u.x);
      u.y = fmaf(xr[i], w.y, u.y);
      u.z = fmaf(xr[i], w.z, u.z);
      u.w = fmaf(xr[i], w.w, u.w);
    }
    res[2 * co]     = pack_f16(u.x, u.y);
    res[2 * co + 1] = pack_f16(u.z, u.w);
  }
  {
    // LDS row stride 44 dwords: 16B-aligned; lane stride 44 == 12 mod 32
    // -> 8 rotating 4-bank groups -> b128 writes at LDS line rate.
    uint4* row = (uint4*)(St + threadIdx.x * 44);
    #pragma unroll
    for (int k = 0; k < 10; ++k)
      row[k] = make_uint4(res[4*k], res[4*k+1], res[4*k+2], res[4*k+3]);
  }
  __syncthreads();
  // flush: global uint4 f covers dwords [4f,4f+4); owner t' = f/10 holds them
  // at LDS row tid(t') = (t'>>1) + (t'&1)*128. Stores are linear/coalesced.
  uint4* dst = (uint4*)(U + (size_t)r * (BH_ * UROW));
  #pragma unroll
  for (int k2 = 0; k2 < 10; ++k2){
    int f    = k2 * 256 + threadIdx.x;   // 0..2559
    int tp   = f / 10;
    int kk   = f - tp * 10;
    int srow = (tp >> 1) + (tp & 1) * 128;
    dst[f] = *(const uint4*)(St + srow * 44 + kk * 4);
  }
}

// ---------- fused routing pass ----------
// MODE 0: c = softmax(b_in[r]) inline (no v);         s0 += c*u
// MODE 1: v=squash(s0); bold=b_in; write bnew->bB;    s1 += c*u
// MODE 2: v=squash(s1); bold=bB;   write bnew->bB;    s2 += c*u
// MODE 3: v=squash(s2); bold=bB;   write c  ->bB;     s3 += c*u
// grid = 128 b_local x 8 r-chunks; thread = (rs in 16, n-lane in 16).
template<int MODE>
__global__ __launch_bounds__(256) void pass_kernel(
    const uint32_t* __restrict__ U,     // [R][BH][80] dwords (fp16 u_hat)
    const float*    __restrict__ b_in,  // [R][NC]
    float*          __restrict__ bB,    // [B][R][NC] (alias of out c-region)
    const float*    __restrict__ s_prev,
    float*          __restrict__ s_out,
    int b0)
{
  const int bl = blockIdx.x >> 3;
  const int b  = b0 + bl;
  const int rc = blockIdx.x & 7;
  const int n  = threadIdx.x & 15;
  const int rs = threadIdx.x >> 4;
  const int nn = (n < NC_) ? n : (NC_ - 1);

  float vreg[16];
  if (MODE != 0){
    // v = squash(s_prev) computed in-block (s_prev final at kernel boundary)
    const float* sp = s_prev + b * 160 + nn * 16;
    float ss = 0.f;
    #pragma unroll
    for (int o = 0; o < 16; ++o){ float t = sp[o]; vreg[o] = t; ss = fmaf(t, t, ss); }
    float f = sqrtf(ss) / (1.f + ss + 1e-8f);
    #pragma unroll
    for (int o = 0; o < 16; ++o) vreg[o] *= f;
  }
  float acc[16];
  #pragma unroll
  for (int o = 0; o < 16; ++o) acc[o] = 0.f;

  const int r0 = rc * 256;
  for (int rr = 0; rr < 16; ++rr){
    const int r = r0 + rr * 16 + rs;
    // 16 n-lanes read 512B contiguous (L3-resident)
    const uint4* up = (const uint4*)(U + ((size_t)r * BH_ + bl) * UROW + n * 8);
    float uf[16];
    unpack8(up[0], uf);
    unpack8(up[1], uf + 8);
    const size_t rowg = (size_t)b * R_ + r;

    float c;
    if (MODE == 0){
      float bold = b_in[r * NC_ + nn];
      float bnew = (n < NC_) ? bold : -1e30f;
      float m = rmax16(bnew);
      float e = __expf(bnew - m);
      float sum = rsum16(e);
      c = e / sum;
    } else {
      float t = 0.f;
      #pragma unroll
      for (int o = 0; o < 16; ++o) t = fmaf(uf[o], vreg[o], t);
      float bold = (MODE == 1) ? b_in[r * NC_ + nn] : bB[rowg * NC_ + nn];
      float bnew = (n < NC_) ? (bold + t) : -1e30f;
      float m = rmax16(bnew);
      float e = __expf(bnew - m);
      float sum = rsum16(e);
      c = e / sum;
      if (MODE == 3){
        if (n < NC_) bB[rowg * NC_ + n] = c;      // final c output
      } else {
        if (n < NC_) bB[rowg * NC_ + n] = bnew;
      }
    }
    #pragma unroll
    for (int o = 0; o < 16; ++o) acc[o] = fmaf(c, uf[o], acc[o]);
  }

  // block reduction over 16 rs partials, then one atomic per (n,o)
  __shared__ float sd[16 * 16 * 17];
  #pragma unroll
  for (int o = 0; o < 16; ++o) sd[rs * 272 + n * 17 + o] = acc[o];
  __syncthreads();
  const int n2 = threadIdx.x >> 4;
  const int o2 = threadIdx.x & 15;
  if (n2 < NC_){
    float tot = 0.f;
    #pragma unroll
    for (int k = 0; k < 16; ++k) tot += sd[k * 272 + n2 * 17 + o2];
    atomicAdd(&s_out[b * 160 + n2 * 16 + o2], tot);
  }
}

// ---------- final squash: v_out = squash(s3) ----------
__global__ __launch_bounds__(256) void squash_final(const float* __restrict__ s,
                                                    float* __restrict__ vout){
  int g = blockIdx.x * 256 + threadIdx.x;   // 16 lanes per (b,n) row
  float xv = s[g];
  float ss = rsum16(xv * xv);
  float norm = sqrtf(ss);
  vout[g] = (norm / (1.f + ss + 1e-8f)) * xv;
}

extern "C" void kernel_launch(void* const* d_in, const int* in_sizes, int n_in,
                              void* d_out, int out_size, void* d_ws, size_t ws_size,
                              hipStream_t stream){
  const float* x    = (const float*)d_in[0];   // [256,2048,8]
  const float* W    = (const float*)d_in[1];   // [2048,8,160]
  const float* b_in = (const float*)d_in[2];   // [2048,10]
  float* out = (float*)d_out;
  float* out_v = out;                 // 40960 floats
  float* bB    = out + 40960;         // [B][R][NC] — also the c output region

  char* w = (char*)d_ws;
  uint32_t* U = (uint32_t*)w;                      // 2048*128*80*4 = 83,886,080 B
  float* s0 = (float*)(w + 83886080);              // 4 x 163,840 B s-chain
  float* s1 = s0 + 40960;
  float* s2 = s1 + 40960;
  float* s3 = s2 + 40960;

  hipMemsetAsync(s0, 0, 4 * 40960 * sizeof(float), stream);
  for (int h = 0; h < 2; ++h){
    const int b0 = h * BH_;
    uhat_kernel<<<R_, 256, 0, stream>>>(x, W, U, b0);
    pass_kernel<0><<<1024, 256, 0, stream>>>(U, b_in, bB, s0, s0, b0);
    pass_kernel<1><<<1024, 256, 0, stream>>>(U, b_in, bB, s0, s1, b0);
    pass_kernel<2><<<1024, 256, 0, stream>>>(U, b_in, bB, s1, s2, b0);
    pass_kernel<3><<<1024, 256, 0, stream>>>(U, b_in, bB, s2, s3, b0);
  }
  squash_final<<<160, 256, 0, stream>>>(s3, out_v);
}